// Round 15
// baseline (220.286 us; speedup 1.0000x reference)
//
#include <hip/hip_runtime.h>
#include <math.h>

#define N_ATOMS  100000
#define N_BOND   150000
#define N_ANGLE  200000
#define N_IMP     50000
#define N_PROP   100000
#define M3       (3 * N_ATOMS)          // 300000 coordinate rows

#define NGRP      4                     // batch groups (was 8): halves TA line visits
#define GSTRIDE16 (N_ATOMS * 16)        // dwords per slab (6.4 MB; ~60% of 4MB XCD L2)
#define N_TILES   (N_ATOMS / 32)        // 3125 transpose tiles

#define EPS_GUARD 1e-12f                // fp8 collision guard

// ---- wave partition within a batch-group: 1280 blocks -> 320 blocks/group
// ---- -> 1280 waves/group, type-specialized (counts ~ VALU cost). (256,5).
// ---- TRIP odd for the depth-2 ping-pong.
#define WB_B 141                         // bond  waves/group, trip 23 (3243>=3125)
#define WB_A 481                         // angle waves/group, trip 13 (6253>=6250)
#define WB_I 241                         // improper,          trip 13 (3133>=3125)
#define WB_P 417                         // proper,            trip 15 (6255>=6250)
#define OFF_A (WB_B)                     // 141
#define OFF_I (WB_B + WB_A)              // 622
#define OFF_P (WB_B + WB_A + WB_I)       // 863  (sum 1280)

// d_ws layout (bytes): pos16 @0 (25.6MB, 4 slabs, pair-interleaved); params after
#define OFF_BONDP (26u << 20)
#define OFF_ANGP  (29u << 20)
#define OFF_IMPP  (31u << 20)
#define OFF_PROPP (32u << 20)

typedef float v2f __attribute__((ext_vector_type(2)));
struct V3P { v2f x, y, z; };             // 3D vector for a batch-PAIR (lo,hi)

__device__ __forceinline__ int imin(int a, int b) { return (a < b) ? a : b; }

__device__ __forceinline__ V3P subP(V3P a, V3P b) { return V3P{a.x-b.x, a.y-b.y, a.z-b.z}; }
__device__ __forceinline__ v2f dotP(V3P a, V3P b) { return a.x*b.x + a.y*b.y + a.z*b.z; }
__device__ __forceinline__ V3P scaleP(V3P a, v2f s) { return V3P{a.x*s, a.y*s, a.z*s}; }
__device__ __forceinline__ V3P crossP(V3P a, V3P b) {
    return V3P{a.y*b.z - a.z*b.y, a.z*b.x - a.x*b.z, a.x*b.y - a.y*b.x};
}

__device__ __forceinline__ float grcp(float x) { return __builtin_amdgcn_rcpf(fmaxf(x, EPS_GUARD)); }
__device__ __forceinline__ float grsq(float x) { return __builtin_amdgcn_rsqf(fmaxf(x, EPS_GUARD)); }

__device__ __forceinline__ float fast_acos(float x) {
    float ax = fabsf(x);
    float r  = sqrtf(fmaxf(0.0f, 1.0f - ax));
    float p  = fmaf(fmaf(fmaf(-0.0187293f, ax, 0.0742610f), ax, -0.2121144f), ax, 1.5707288f);
    float v  = r * p;
    return (x < 0.0f) ? (3.14159265358979f - v) : v;
}

__device__ __forceinline__ float fast_atan2(float y, float x) {
    float ax = fabsf(x), ay = fabsf(y);
    float mn = fminf(ax, ay), mx = fmaxf(ax, ay);
    float a  = mn * grcp(mx);
    float s  = a * a;
    float p  = fmaf(s, fmaf(s, fmaf(s, fmaf(s, fmaf(s, -0.01172120f, 0.05265332f),
                     -0.11643287f), 0.19354346f), -0.33262347f), 0.99997726f);
    float t  = a * p;
    if (ay > ax)  t = 1.57079632679490f - t;
    if (x < 0.0f) t = 3.14159265358979f - t;
    return copysignf(t, y);
}

// uint4 word = 2 pair-interleaved batch-pairs:
//   w.x = fp8{x_b0,x_b1,y_b0,y_b1}  w.y = fp8{z_b0,z_b1,0,0}
//   w.z = fp8{x_b2,x_b3,y_b2,y_b3}  w.w = fp8{z_b2,z_b3,0,0}
__device__ __forceinline__ V3P upA(uint4 w) {
    V3P r;
    r.x = __builtin_amdgcn_cvt_pk_f32_fp8((int)w.x, false);
    r.y = __builtin_amdgcn_cvt_pk_f32_fp8((int)w.x, true);
    r.z = __builtin_amdgcn_cvt_pk_f32_fp8((int)w.y, false);
    return r;
}
__device__ __forceinline__ V3P upB(uint4 w) {
    V3P r;
    r.x = __builtin_amdgcn_cvt_pk_f32_fp8((int)w.z, false);
    r.y = __builtin_amdgcn_cvt_pk_f32_fp8((int)w.z, true);
    r.z = __builtin_amdgcn_cvt_pk_f32_fp8((int)w.w, false);
    return r;
}

// ---- shared geometry helpers (batch-pair v2f math) ----
__device__ __forceinline__ v2f angleth(V3P p0, V3P pm, V3P p2) {
    V3P v1 = subP(p0, pm), v2 = subP(p2, pm);
    v2f num = dotP(v1, v2);
    v2f nn  = dotP(v1, v1) * dotP(v2, v2);
    float cl = fminf(1.0f, fmaxf(-1.0f, num.x * grsq(nn.x)));
    float ch = fminf(1.0f, fmaxf(-1.0f, num.y * grsq(nn.y)));
    return (v2f){fast_acos(cl), fast_acos(ch)};
}
__device__ __forceinline__ v2f dihed(V3P a0, V3P a1, V3P a2, V3P a3) {
    V3P b0 = subP(a0, a1), b1 = subP(a2, a1), b2 = subP(a3, a2);
    v2f nb1 = dotP(b1, b1);
    v2f inv = (v2f){grsq(nb1.x), grsq(nb1.y)};
    b1 = scaleP(b1, inv);
    V3P v = subP(b0, scaleP(b1, dotP(b0, b1)));
    V3P w = subP(b2, scaleP(b1, dotP(b2, b1)));
    v2f x = dotP(v, w);
    v2f y = dotP(crossP(b1, v), w);
    return (v2f){fast_atan2(y.x, x.x), fast_atan2(y.y, x.y)};
}
__device__ __forceinline__ v2f properU(V3P a0, V3P a1, V3P a2, V3P a3) {
    V3P b0 = subP(a0, a1), b1 = subP(a2, a1), b2 = subP(a3, a2);
    v2f u   = dotP(b1, b1);
    v2f inv = (v2f){grcp(u.x), grcp(u.y)};
    V3P v = subP(b0, scaleP(b1, dotP(b0, b1) * inv));
    V3P w = subP(b2, scaleP(b1, dotP(b2, b1) * inv));
    v2f x  = dotP(v, w);
    v2f yp = dotP(crossP(b1, v), w);
    v2f tt = u * x * x;
    v2f den = tt + yp * yp;
    return tt * (v2f){grcp(den.x), grcp(den.y)};     // caller multiplies 2*pc
}

// ---- fused pre-pass: transpose+quantize (4-group, 64B atom rows) + params + out zero
__global__ __launch_bounds__(256) void pre_kernel(
    const float* __restrict__ pos, unsigned int* __restrict__ pos16,
    const int* __restrict__ bond_type,     const float* __restrict__ equ_bond,
    const float* __restrict__ k_bond,
    const int* __restrict__ angle_type,    const float* __restrict__ equ_angle,
    const float* __restrict__ k_angle,
    const int* __restrict__ improper_type, const float* __restrict__ equ_improper,
    const float* __restrict__ k_improper,
    const float* __restrict__ proper_const, const float* __restrict__ proper_mul,
    const float* __restrict__ proper_phase,
    float2* __restrict__ bondP, float2* __restrict__ angleP,
    float2* __restrict__ impP,  float4* __restrict__ propP,
    float* __restrict__ out, int out_n)
{
    __shared__ float tile[64][97];
    if (blockIdx.x < N_TILES) {
        const int t    = threadIdx.x;
        const int b    = t >> 2;
        const int j    = t & 3;
        const int lane = t & 63;
        const int a0   = blockIdx.x * 32;

        const float* __restrict__ src = pos + (size_t)b * M3 + 3 * a0;
        #pragma unroll
        for (int i = 0; i < 6; ++i) {
            const int f4 = j + 4 * i;
            const float4 v = *(const float4*)(src + 4 * f4);
            tile[b][4*f4 + 0] = v.x;
            tile[b][4*f4 + 1] = v.y;
            tile[b][4*f4 + 2] = v.z;
            tile[b][4*f4 + 3] = v.w;
        }
        __syncthreads();

        // pack: per (group, it): slot = it*64+lane -> (al, jq); store one uint4
        // (4 batches, pair-interleaved). 64 lanes = 1KB contiguous per store op.
        #pragma unroll
        for (int g = 0; g < NGRP; ++g) {
            #pragma unroll
            for (int it = 0; it < 2; ++it) {
                const int slot = it * 64 + lane;
                const int al = slot >> 2;        // atom-in-tile 0..31
                const int jq = slot & 3;         // batch-quad 0..3
                const int b0 = g * 16 + jq * 4;  // first of 4 source batches
                uint4 w;
                int wx = 0, wy = 0, wz = 0, ww = 0;
                wx = __builtin_amdgcn_cvt_pk_fp8_f32(tile[b0+0][3*al+0], tile[b0+1][3*al+0], wx, false);
                wx = __builtin_amdgcn_cvt_pk_fp8_f32(tile[b0+0][3*al+1], tile[b0+1][3*al+1], wx, true);
                wy = __builtin_amdgcn_cvt_pk_fp8_f32(tile[b0+0][3*al+2], tile[b0+1][3*al+2], wy, false);
                wz = __builtin_amdgcn_cvt_pk_fp8_f32(tile[b0+2][3*al+0], tile[b0+3][3*al+0], wz, false);
                wz = __builtin_amdgcn_cvt_pk_fp8_f32(tile[b0+2][3*al+1], tile[b0+3][3*al+1], wz, true);
                ww = __builtin_amdgcn_cvt_pk_fp8_f32(tile[b0+2][3*al+2], tile[b0+3][3*al+2], ww, false);
                w.x = (unsigned)wx; w.y = (unsigned)wy; w.z = (unsigned)wz; w.w = (unsigned)ww;
                *(uint4*)&pos16[(size_t)g * GSTRIDE16 + (size_t)(a0 + al) * 16 + jq * 4] = w;
            }
        }
    } else {
        const int i = (blockIdx.x - N_TILES) * 256 + threadIdx.x;
        if (i < out_n)   out[i] = 0.0f;      // replaces the hipMemsetAsync dispatch
        if (i < N_BOND)  { int t = bond_type[i];     bondP[i]  = make_float2(equ_bond[t],     k_bond[t]); }
        if (i < N_ANGLE) { int t = angle_type[i];    angleP[i] = make_float2(equ_angle[t],    k_angle[t]); }
        if (i < N_IMP)   { int t = improper_type[i]; impP[i]   = make_float2(equ_improper[t], k_improper[t]); }
        if (i < N_PROP)  { propP[i] = make_float4(proper_const[i], proper_mul[i], proper_phase[i], 0.0f); }
    }
}

// ---- uint4 gathers: lane = 16 term-slots x 4 batch-quads; 16B (4 batches)/lane;
// ---- 4 jq lanes share one 64B atom row -> 16 full-line visits per instruction.
template<int NW>
__device__ __forceinline__ void gath(const unsigned int* __restrict__ baseg,
                                     const int* ii, int jq, uint4* wv) {
    #pragma unroll
    for (int k = 0; k < NW; ++k)
        wv[k] = *(const uint4*)(baseg + (size_t)((unsigned)ii[k] * 16u + (unsigned)(jq * 4)));
}

// ---- type tags: q in [0,16); each lane-slot owns Td/2 terms x 4 batches ----
struct BondT {                                 // 48 terms/chunk: 16 slots x 3 terms
    static constexpr int NC = 3125, NI = 6, NW = 6;
    __device__ static void loadIdx(const int* __restrict__ idcs, int l, int q, int* ii) {
        const int2* p = (const int2*)idcs + (l * 48 + q * 3);   // 3 pairs
        int2 a = p[0], b = p[1], c = p[2];
        ii[0]=a.x; ii[1]=a.y; ii[2]=b.x; ii[3]=b.y; ii[4]=c.x; ii[5]=c.y;
    }
    __device__ static void comp(const uint4* wv, const float* prm, int l, int q,
                                float m, v2f& eA, v2f& eB) {
        const float2* pp = (const float2*)prm + (l * 48 + q * 3);
        #pragma unroll
        for (int i = 0; i < 3; ++i) {
            const float2 P = pp[i];
            const float mk = m * P.y;
            V3P dA = subP(upA(wv[2*i]), upA(wv[2*i + 1]));
            v2f a2 = dotP(dA, dA);
            v2f da = (v2f){sqrtf(a2.x), sqrtf(a2.y)} - P.x;
            eA += mk * (da * da);
            V3P dB = subP(upB(wv[2*i]), upB(wv[2*i + 1]));
            v2f b2 = dotP(dB, dB);
            v2f db = (v2f){sqrtf(b2.x), sqrtf(b2.y)} - P.x;
            eB += mk * (db * db);
        }
    }
};

struct AngleT {                                // 32 terms/chunk: 16 slots x 2 terms
    static constexpr int NC = 6250, NI = 6, NW = 6;
    __device__ static void loadIdx(const int* __restrict__ idcs, int l, int q, int* ii) {
        const int2* p = (const int2*)idcs + (l * 48 + q * 3);   // 2 terms x 3 ints
        int2 a = p[0], b = p[1], c = p[2];
        ii[0]=a.x; ii[1]=a.y; ii[2]=b.x; ii[3]=b.y; ii[4]=c.x; ii[5]=c.y;
    }
    __device__ static void comp(const uint4* wv, const float* prm, int l, int q,
                                float m, v2f& eA, v2f& eB) {
        const float4 P = *((const float4*)prm + (l * 16 + q));  // 2 x (eq,k)
        #pragma unroll
        for (int i = 0; i < 2; ++i) {
            const float eq = i ? P.z : P.x;
            const float mk = m * (i ? P.w : P.y);
            v2f thA = angleth(upA(wv[3*i]), upA(wv[3*i + 1]), upA(wv[3*i + 2]));
            v2f dA = thA - eq;
            eA += mk * (dA * dA);
            v2f thB = angleth(upB(wv[3*i]), upB(wv[3*i + 1]), upB(wv[3*i + 2]));
            v2f dB = thB - eq;
            eB += mk * (dB * dB);
        }
    }
};

struct ImpT {                                  // 16 terms/chunk: 16 slots x 1 term
    static constexpr int NC = 3125, NI = 4, NW = 4;
    __device__ static void loadIdx(const int* __restrict__ idcs, int l, int q, int* ii) {
        const int4 p = *((const int4*)idcs + (l * 16 + q));
        ii[0]=p.x; ii[1]=p.y; ii[2]=p.z; ii[3]=p.w;
    }
    __device__ static void comp(const uint4* wv, const float* prm, int l, int q,
                                float m, v2f& eA, v2f& eB) {
        const float2 P = ((const float2*)prm)[l * 16 + q];
        const float mk = m * P.y;
        v2f phA = dihed(upA(wv[0]), upA(wv[1]), upA(wv[2]), upA(wv[3]));
        v2f dA = phA - P.x;
        eA += mk * (dA * dA);
        v2f phB = dihed(upB(wv[0]), upB(wv[1]), upB(wv[2]), upB(wv[3]));
        v2f dB = phB - P.x;
        eB += mk * (dB * dB);
    }
};

struct PropT {                                 // 16 terms/chunk: 16 slots x 1 term
    static constexpr int NC = 6250, NI = 4, NW = 4;
    __device__ static void loadIdx(const int* __restrict__ idcs, int l, int q, int* ii) {
        const int4 p = *((const int4*)idcs + (l * 16 + q));
        ii[0]=p.x; ii[1]=p.y; ii[2]=p.z; ii[3]=p.w;
    }
    __device__ static void comp(const uint4* wv, const float* prm, int l, int q,
                                float m, v2f& eA, v2f& eB) {
        const float4 P = ((const float4*)prm)[l * 16 + q];      // (pc, pm, ph, 0)
        if (P.y == 2.0f && P.z == 0.0f) {                       // uniform branch (per-term)
            const float mk = m * 2.0f * P.x;
            eA += mk * properU(upA(wv[0]), upA(wv[1]), upA(wv[2]), upA(wv[3]));
            eB += mk * properU(upB(wv[0]), upB(wv[1]), upB(wv[2]), upB(wv[3]));
        } else {
            const float mk = m * P.x;
            v2f phA = dihed(upA(wv[0]), upA(wv[1]), upA(wv[2]), upA(wv[3]));
            eA += mk * ((v2f){1.0f + cosf(P.y * phA.x - P.z), 1.0f + cosf(P.y * phA.y - P.z)});
            v2f phB = dihed(upB(wv[0]), upB(wv[1]), upB(wv[2]), upB(wv[3]));
            eB += mk * ((v2f){1.0f + cosf(P.y * phB.x - P.z), 1.0f + cosf(P.y * phB.y - P.z)});
        }
    }
};

// ---- depth-2 ping-pong pipeline (proven skeleton); TRIP odd; tail chunks
// ---- clamped+masked so every ii/wv write is UNCONDITIONAL (spill-proof).
template<class T, int W, int TRIP>
__device__ __forceinline__ void run_type(const unsigned int* __restrict__ baseg,
                                         const int* __restrict__ idcs,
                                         const float* __restrict__ prm,
                                         int widx, int q, int jq, v2f& eA, v2f& eB)
{
    static_assert(TRIP % 2 == 1, "TRIP must be odd");
    constexpr int NPAIR = (TRIP - 1) / 2;
    constexpr int NCm1  = T::NC - 1;
    int ii0[T::NI], ii1[T::NI];
    uint4 wv0[T::NW], wv1[T::NW];

    int lr  = widx;                      // iter 0 chunk (widx < W <= NC: valid)
    int lrB = widx + W;                  // iter 1 chunk
    T::loadIdx(idcs, lr, q, ii0);
    T::loadIdx(idcs, imin(lrB, NCm1), q, ii1);
    gath<T::NW>(baseg, ii0, jq, wv0);

    #pragma unroll 1
    for (int p = 0; p < NPAIR; ++p) {
        gath<T::NW>(baseg, ii1, jq, wv1);
        const int lr2 = lr + 2 * W;
        T::loadIdx(idcs, imin(lr2, NCm1), q, ii0);
        T::comp(wv0, prm, imin(lr, NCm1), q, (lr <= NCm1) ? 1.0f : 0.0f, eA, eB);

        gath<T::NW>(baseg, ii0, jq, wv0);
        const int lr3 = lr + 3 * W;
        T::loadIdx(idcs, imin(lr3, NCm1), q, ii1);
        T::comp(wv1, prm, imin(lrB, NCm1), q, (lrB <= NCm1) ? 1.0f : 0.0f, eA, eB);

        lr = lr2; lrB = lr3;
    }
    // epilogue: wv0 already holds iter (2*NPAIR)'s gathers
    T::comp(wv0, prm, imin(lr, NCm1), q, (lr <= NCm1) ? 1.0f : 0.0f, eA, eB);
}

// ---------------- main: 4 batch-groups (XCD pairs {g,g+4} share one 6.4MB slab),
// ---------------- type-specialized waves, uint4 gathers, depth-2. grid 1280, (256,5).
__global__ __launch_bounds__(256, 5) void energy_kernel(
    const unsigned int* __restrict__ pos16,
    const int*   __restrict__ bond_idcs,  const int* __restrict__ angle_idcs,
    const int*   __restrict__ improper_idcs, const int* __restrict__ proper_idcs,
    const float* __restrict__ bondP, const float* __restrict__ angleP,
    const float* __restrict__ impP,  const float* __restrict__ propP,
    float* __restrict__ out)
{
    const int lane = threadIdx.x & 63;
    const int q    = lane >> 2;                                          // term slot [0,16)
    const int jq   = lane & 3;                                           // batch-quad [0,4)
    const int wid  = __builtin_amdgcn_readfirstlane(threadIdx.x >> 6);   // scalar
    const int g    = blockIdx.x & 3;                                     // batch group
    const int wig  = (blockIdx.x >> 2) * 4 + wid;                        // wave-in-group [0,1280)

    const unsigned int* __restrict__ baseg = pos16 + (size_t)g * GSTRIDE16;

    v2f eA = {0.0f, 0.0f};                       // batches g*16 + jq*4 + {0,1}
    v2f eB = {0.0f, 0.0f};                       // batches g*16 + jq*4 + {2,3}
    if (wig < OFF_A)                                 // bond cohort
        run_type<BondT,  WB_B, 23>(baseg, bond_idcs,     bondP,  wig,         q, jq, eA, eB);
    else if (wig < OFF_I)                            // angle cohort
        run_type<AngleT, WB_A, 13>(baseg, angle_idcs,    angleP, wig - OFF_A, q, jq, eA, eB);
    else if (wig < OFF_P)                            // improper cohort
        run_type<ImpT,   WB_I, 13>(baseg, improper_idcs, impP,   wig - OFF_I, q, jq, eA, eB);
    else                                             // proper cohort
        run_type<PropT,  WB_P, 15>(baseg, proper_idcs,   propP,  wig - OFF_P, q, jq, eA, eB);

    // reduce across the 16 term-slots (same jq): xor-butterfly strides 4..32
    #pragma unroll
    for (int s = 4; s <= 32; s <<= 1) {
        eA.x += __shfl_xor(eA.x, s);
        eA.y += __shfl_xor(eA.y, s);
        eB.x += __shfl_xor(eB.x, s);
        eB.y += __shfl_xor(eB.y, s);
    }

    __shared__ float4 red[4][4];
    if (lane < 4) red[wid][lane] = make_float4(eA.x, eA.y, eB.x, eB.y);
    __syncthreads();
    if (wid == 0 && lane < 4) {
        float4 s0 = red[0][lane], s1 = red[1][lane], s2 = red[2][lane], s3 = red[3][lane];
        atomicAdd(&out[g * 16 + lane * 4 + 0], s0.x + s1.x + s2.x + s3.x);
        atomicAdd(&out[g * 16 + lane * 4 + 1], s0.y + s1.y + s2.y + s3.y);
        atomicAdd(&out[g * 16 + lane * 4 + 2], s0.z + s1.z + s2.z + s3.z);
        atomicAdd(&out[g * 16 + lane * 4 + 3], s0.w + s1.w + s2.w + s3.w);
    }
}

extern "C" void kernel_launch(void* const* d_in, const int* in_sizes, int n_in,
                              void* d_out, int out_size, void* d_ws, size_t ws_size,
                              hipStream_t stream) {
    const float* pos           = (const float*)d_in[0];
    const int*   bond_idcs     = (const int*)  d_in[1];
    const int*   bond_type     = (const int*)  d_in[2];
    const float* equ_bond      = (const float*)d_in[3];
    const float* k_bond        = (const float*)d_in[4];
    const int*   angle_idcs    = (const int*)  d_in[5];
    const int*   angle_type    = (const int*)  d_in[6];
    const float* equ_angle     = (const float*)d_in[7];
    const float* k_angle       = (const float*)d_in[8];
    const int*   improper_idcs = (const int*)  d_in[9];
    const int*   improper_type = (const int*)  d_in[10];
    const float* equ_improper  = (const float*)d_in[11];
    const float* k_improper    = (const float*)d_in[12];
    const int*   proper_idcs   = (const int*)  d_in[13];
    const float* proper_phase  = (const float*)d_in[14];
    const float* proper_const  = (const float*)d_in[15];
    const float* proper_mul    = (const float*)d_in[16];
    float* out = (float*)d_out;

    unsigned int* pos16 = (unsigned int*)d_ws;                       // 25.6 MB, 4 slabs
    float2* bondP  = (float2*)((char*)d_ws + OFF_BONDP);             // 1.2 MB
    float2* angleP = (float2*)((char*)d_ws + OFF_ANGP);              // 1.6 MB
    float2* impP   = (float2*)((char*)d_ws + OFF_IMPP);             // 0.4 MB
    float4* propP  = (float4*)((char*)d_ws + OFF_PROPP);             // 1.6 MB

    // fused pre-pass: 3125 transpose tiles + 782 param-fuse blocks (+ out zero)
    pre_kernel<<<dim3(N_TILES + (N_ANGLE + 255) / 256), dim3(256), 0, stream>>>(
        pos, pos16,
        bond_type, equ_bond, k_bond,
        angle_type, equ_angle, k_angle,
        improper_type, equ_improper, k_improper,
        proper_const, proper_mul, proper_phase,
        bondP, angleP, impP, propP,
        out, out_size);

    energy_kernel<<<dim3(1280), dim3(256), 0, stream>>>(
        pos16, bond_idcs, angle_idcs, improper_idcs, proper_idcs,
        (const float*)bondP, (const float*)angleP, (const float*)impP, (const float*)propP,
        out);
}